// Round 5
// baseline (563.097 us; speedup 1.0000x reference)
//
#include <hip/hip_runtime.h>

namespace {

constexpr int HW = 16384;   // pixels per image
constexpr int C  = 192;
constexpr int C3 = 576;
constexpr int K  = 192;

using bf16x8 = __attribute__((ext_vector_type(8))) short;
using f32x4  = __attribute__((ext_vector_type(4))) float;

__device__ inline unsigned short f2bf(float f) {
  unsigned u = __float_as_uint(f);
  unsigned r = (u + 0x7fff + ((u >> 16) & 1)) >> 16;
  return (unsigned short)r;
}
__device__ inline float bf2f(unsigned short b) {
  return __uint_as_float(((unsigned)b) << 16);
}

// ---- split fp32 -> bf16 hi/lo (4 elems/thread), all images -----------------
__global__ __launch_bounds__(256) void cvt_split(const float* __restrict__ in,
                                                 unsigned short* __restrict__ hi,
                                                 unsigned short* __restrict__ lo) {
  const int t = blockIdx.x * 256 + threadIdx.x;
  const float4 v = ((const float4*)in)[t];
  const float vv[4] = {v.x, v.y, v.z, v.w};
  unsigned short h[4], l[4];
#pragma unroll
  for (int j = 0; j < 4; ++j) {
    h[j] = f2bf(vv[j]);
    l[j] = f2bf(vv[j] - bf2f(h[j]));
  }
  ((ushort4*)hi)[t] = make_ushort4(h[0], h[1], h[2], h[3]);
  ((ushort4*)lo)[t] = make_ushort4(l[0], l[1], l[2], l[3]);
}

// ---- transpose + split qkv weights: [192,576] -> hi/lo [576][192] ----------
__global__ __launch_bounds__(256) void cvt_wqkv(const float* __restrict__ wqkv,
                                                unsigned short* __restrict__ wqh,
                                                unsigned short* __restrict__ wql) {
  const int t = blockIdx.x * 256 + threadIdx.x;  // 0 .. 576*192-1
  const int n = t / 192;
  const int k = t % 192;
  const float v = wqkv[k * C3 + n];
  const unsigned short h = f2bf(v);
  wqh[n * 192 + k] = h;
  wql[n * 192 + k] = f2bf(v - bf2f(h));
}

// ---- MFMA GEMM: Co[M,N] = A[M,192] @ Bt[N,192]^T, 3-pass bf16 split --------
// PERB: B indexed per image (m0>>14).
template <int N, bool PERB>
__global__ __launch_bounds__(256, 3) void gemm_mfma(const unsigned short* __restrict__ Ah,
                                                    const unsigned short* __restrict__ Al,
                                                    const unsigned short* __restrict__ Bh,
                                                    const unsigned short* __restrict__ Bl,
                                                    float* __restrict__ Co) {
  __shared__ __align__(16) unsigned short sAh[2][128 * 32];
  __shared__ __align__(16) unsigned short sAl[2][128 * 32];
  __shared__ __align__(16) unsigned short sBh[2][64 * 32];
  __shared__ __align__(16) unsigned short sBl[2][64 * 32];
  const int t = threadIdx.x;
  const int lane = t & 63;
  const int wid = t >> 6;
  const int m0 = blockIdx.x * 128;
  const int n0 = blockIdx.y * 64;
  const size_t boff = PERB ? (size_t)(m0 >> 14) * (192 * 192) : 0;
  const int wr = wid >> 1, wc = wid & 1;
  const int fr_row = lane & 15;
  const int fr_swz = ((lane >> 4) ^ (lane & 3)) << 3;

  f32x4 acc[4][2] = {};
  bf16x8 rg[6];

  auto stage_load = [&](int k0) {
#pragma unroll
    for (int r = 0; r < 2; ++r) {
      const int idx = t + (r << 8);
      const int row = idx >> 2, sl = idx & 3;
      const size_t go = (size_t)(m0 + row) * K + k0 + (sl << 3);
      rg[r]     = *(const bf16x8*)&Ah[go];
      rg[2 + r] = *(const bf16x8*)&Al[go];
    }
    {
      const int row = t >> 2, sl = t & 3;
      const size_t go = boff + (size_t)(n0 + row) * K + k0 + (sl << 3);
      rg[4] = *(const bf16x8*)&Bh[go];
      rg[5] = *(const bf16x8*)&Bl[go];
    }
  };
  auto stage_write = [&](int buf) {
#pragma unroll
    for (int r = 0; r < 2; ++r) {
      const int idx = t + (r << 8);
      const int row = idx >> 2, sl = idx & 3;
      const int ph = row * 32 + ((sl ^ (row & 3)) << 3);
      *(bf16x8*)&sAh[buf][ph] = rg[r];
      *(bf16x8*)&sAl[buf][ph] = rg[2 + r];
    }
    {
      const int row = t >> 2, sl = t & 3;
      const int ph = row * 32 + ((sl ^ (row & 3)) << 3);
      *(bf16x8*)&sBh[buf][ph] = rg[4];
      *(bf16x8*)&sBl[buf][ph] = rg[5];
    }
  };

  stage_load(0);
  stage_write(0);
  __syncthreads();
#pragma unroll
  for (int ks = 0; ks < 6; ++ks) {
    if (ks < 5) stage_load((ks + 1) * 32);
    {
      const int buf = ks & 1;
      bf16x8 fah[4], fal[4], fbh[2], fbl[2];
#pragma unroll
      for (int i = 0; i < 4; ++i) {
        const int row = wr * 64 + i * 16 + fr_row;
        fah[i] = *(const bf16x8*)&sAh[buf][row * 32 + fr_swz];
        fal[i] = *(const bf16x8*)&sAl[buf][row * 32 + fr_swz];
      }
#pragma unroll
      for (int j = 0; j < 2; ++j) {
        const int row = wc * 32 + j * 16 + fr_row;
        fbh[j] = *(const bf16x8*)&sBh[buf][row * 32 + fr_swz];
        fbl[j] = *(const bf16x8*)&sBl[buf][row * 32 + fr_swz];
      }
#pragma unroll
      for (int i = 0; i < 4; ++i)
#pragma unroll
        for (int j = 0; j < 2; ++j) {
          acc[i][j] = __builtin_amdgcn_mfma_f32_16x16x32_bf16(fah[i], fbh[j], acc[i][j], 0, 0, 0);
          acc[i][j] = __builtin_amdgcn_mfma_f32_16x16x32_bf16(fah[i], fbl[j], acc[i][j], 0, 0, 0);
          acc[i][j] = __builtin_amdgcn_mfma_f32_16x16x32_bf16(fal[i], fbh[j], acc[i][j], 0, 0, 0);
        }
    }
    if (ks < 5) {
      __syncthreads();
      stage_write((ks + 1) & 1);
      __syncthreads();
    }
  }

  const int er = (lane >> 4) << 2;  // C/D: col=lane&15, row=(lane>>4)*4+reg
  const int ec = lane & 15;
#pragma unroll
  for (int i = 0; i < 4; ++i)
#pragma unroll
    for (int j = 0; j < 2; ++j) {
      float* cp = &Co[(size_t)(m0 + wr * 64 + i * 16 + er) * N + n0 + wc * 32 + j * 16 + ec];
#pragma unroll
      for (int r = 0; r < 4; ++r) cp[(size_t)r * N] = acc[i][j][r];
    }
}

// ---- depthwise 3x3 SAME, y-blocked x2; q,k -> fp32 [p][384], v -> bf16 -----
// Each thread: fixed (x, c4), two consecutive y outputs. 12 tap loads up-front
// (ILP), interior fast path has zero clamping/select overhead.
__global__ __launch_bounds__(256) void dwconv3x3_v2(const float* __restrict__ in,
                                                    const float* __restrict__ wdw,
                                                    float* __restrict__ dwq,
                                                    unsigned short* __restrict__ vh,
                                                    unsigned short* __restrict__ vl) {
  const int t = blockIdx.x * 256 + threadIdx.x;
  const int c4 = t % 144;
  const int pix2 = t / 144;          // (img, y-pair, x)
  const int x = pix2 & 127;
  const int yp = (pix2 >> 7) & 63;
  const int img = pix2 >> 13;
  const int y0 = yp * 2;

  // weights: 9 float4 (L1/L2 resident)
  float4 wt[3][3];
#pragma unroll
  for (int i = 0; i < 3; ++i)
#pragma unroll
    for (int j = 0; j < 3; ++j)
      wt[i][j] = *(const float4*)&wdw[(size_t)(i * 3 + j) * C3 + c4 * 4];

  float4 tap[4][3];
  const bool interior = ((unsigned)(x - 1) < 126u) && ((unsigned)(yp - 1) < 62u);
  if (interior) {
    const float* base = &in[((size_t)(img << 14) + (y0 << 7) + x) * C3 + c4 * 4];
#pragma unroll
    for (int i = 0; i < 4; ++i)
#pragma unroll
      for (int j = 0; j < 3; ++j)
        tap[i][j] = *(const float4*)&base[(size_t)((i - 1) * 128 + (j - 1)) * C3];
  } else {
#pragma unroll
    for (int i = 0; i < 4; ++i) {
      const int ry = y0 - 1 + i;
      const int ryc = ry < 0 ? 0 : (ry > 127 ? 127 : ry);
      const bool vy = (unsigned)ry < 128u;
#pragma unroll
      for (int j = 0; j < 3; ++j) {
        const int rx = x - 1 + j;
        const int rxc = rx < 0 ? 0 : (rx > 127 ? 127 : rx);
        float4 v = *(const float4*)&in[((size_t)(img << 14) + (ryc << 7) + rxc) * C3 + c4 * 4];
        if (!(vy && ((unsigned)rx < 128u))) v = make_float4(0.f, 0.f, 0.f, 0.f);
        tap[i][j] = v;
      }
    }
  }

  float4 out0 = make_float4(0.f, 0.f, 0.f, 0.f);
  float4 out1 = make_float4(0.f, 0.f, 0.f, 0.f);
#pragma unroll
  for (int i = 0; i < 3; ++i)
#pragma unroll
    for (int j = 0; j < 3; ++j) {
      const float4 w = wt[i][j];
      const float4 a = tap[i][j];
      const float4 b = tap[i + 1][j];
      out0.x += a.x * w.x; out0.y += a.y * w.y; out0.z += a.z * w.z; out0.w += a.w * w.w;
      out1.x += b.x * w.x; out1.y += b.y * w.y; out1.z += b.z * w.z; out1.w += b.w * w.w;
    }

  const int p0 = (img << 14) + (y0 << 7) + x;
  const int p1 = p0 + 128;
  if (c4 < 96) {
    *(float4*)&dwq[(size_t)p0 * 384 + c4 * 4] = out0;
    *(float4*)&dwq[(size_t)p1 * 384 + c4 * 4] = out1;
  } else {
    const int cc = (c4 - 96) * 4;
    const float v0[4] = {out0.x, out0.y, out0.z, out0.w};
    const float v1[4] = {out1.x, out1.y, out1.z, out1.w};
    ushort4 h0, l0, h1, l1;
    unsigned short *h0p = (unsigned short*)&h0, *l0p = (unsigned short*)&l0;
    unsigned short *h1p = (unsigned short*)&h1, *l1p = (unsigned short*)&l1;
#pragma unroll
    for (int j = 0; j < 4; ++j) {
      unsigned short hb = f2bf(v0[j]);
      h0p[j] = hb; l0p[j] = f2bf(v0[j] - bf2f(hb));
      hb = f2bf(v1[j]);
      h1p[j] = hb; l1p[j] = f2bf(v1[j] - bf2f(hb));
    }
    *(ushort4*)&vh[(size_t)p0 * 192 + cc] = h0;
    *(ushort4*)&vl[(size_t)p0 * 192 + cc] = l0;
    *(ushort4*)&vh[(size_t)p1 * 192 + cc] = h1;
    *(ushort4*)&vl[(size_t)p1 * 192 + cc] = l1;
  }
}

// ------- Gram v2: wave = head, 6x6 cells per lane (8x8 lanes = 48x48) -------
// Block: 256 threads = 4 waves, stages [32px][384ch] fp32 tiles for all heads.
// Each block handles 64 px (2 sub-chunks of 32). Grid (256, NI).
__global__ __launch_bounds__(256) void gram48_v2(const float* __restrict__ dwq,
                                                 float* __restrict__ G,
                                                 float* __restrict__ ssqq,
                                                 float* __restrict__ ssqk) {
  __shared__ float qk[32 * 392];   // [32 px][384 ch + 8 pad]
  const int tid = threadIdx.x;
  const int img = blockIdx.y;
  const int sbase = (img << 14) + blockIdx.x * 64;
  const int lane = tid & 63;
  const int h = tid >> 6;          // wave = head
  const int ri = lane >> 3, ci = lane & 7;
  const int r0 = ri * 6, d0 = ci * 6;
  const int qoff = h * 48 + r0;
  const int koff = 192 + h * 48 + d0;

  float acc[6][6] = {};
  float sq[6] = {}, sk[6] = {};

  for (int sub = 0; sub < 2; ++sub) {
    // stage 32 px x 384 ch (12 float4 per thread)
#pragma unroll
    for (int r = 0; r < 12; ++r) {
      const int idx = tid + r * 256;     // 0..3071
      const int row = idx / 96;
      const int cc4 = idx % 96;
      *(float4*)&qk[row * 392 + cc4 * 4] =
          *(const float4*)&dwq[(size_t)(sbase + sub * 32 + row) * 384 + cc4 * 4];
    }
    __syncthreads();
#pragma unroll 2
    for (int s = 0; s < 32; ++s) {
      const float* rowp = &qk[s * 392];
      float q[6], k[6];
#pragma unroll
      for (int i = 0; i < 3; ++i) {
        const float2 qa = *(const float2*)&rowp[qoff + i * 2];
        const float2 ka = *(const float2*)&rowp[koff + i * 2];
        q[i * 2] = qa.x; q[i * 2 + 1] = qa.y;
        k[i * 2] = ka.x; k[i * 2 + 1] = ka.y;
      }
      if (ci == 0) {
#pragma unroll
        for (int i = 0; i < 6; ++i) sq[i] += q[i] * q[i];
      }
      if (ri == 0) {
#pragma unroll
        for (int j = 0; j < 6; ++j) sk[j] += k[j] * k[j];
      }
#pragma unroll
      for (int i = 0; i < 6; ++i)
#pragma unroll
        for (int j = 0; j < 6; ++j) acc[i][j] += q[i] * k[j];
    }
    __syncthreads();
  }

  float* Gm = &G[(size_t)(img * 4 + h) * 2304];
#pragma unroll
  for (int i = 0; i < 6; ++i)
#pragma unroll
    for (int j = 0; j < 6; ++j) atomicAdd(&Gm[(r0 + i) * 48 + d0 + j], acc[i][j]);
  if (ci == 0) {
#pragma unroll
    for (int i = 0; i < 6; ++i) atomicAdd(&ssqq[img * 192 + h * 48 + r0 + i], sq[i]);
  }
  if (ri == 0) {
#pragma unroll
    for (int j = 0; j < 6; ++j) atomicAdd(&ssqk[img * 192 + h * 48 + d0 + j], sk[j]);
  }
}

// ---- softmax over d of G*temp/(|q||k|), one wave per (img,h,row) -----------
__global__ __launch_bounds__(64) void attn_softmax(const float* __restrict__ G,
                                                   const float* __restrict__ ssqq,
                                                   const float* __restrict__ ssqk,
                                                   const float* __restrict__ temp,
                                                   float* __restrict__ attn) {
  const int r = blockIdx.x;          // 0..47
  const int h = blockIdx.y & 3;
  const int img = blockIdx.y >> 2;
  const int lane = threadIdx.x;
  const size_t base = (size_t)(img * 4 + h) * 2304;
  const float t = temp[h];
  const float qn = ssqq[img * 192 + h * 48 + r];
  float val = -1e30f;
  if (lane < 48) {
    const float kn = ssqk[img * 192 + h * 48 + lane];
    val = G[base + r * 48 + lane] * t * rsqrtf(qn * kn);
  }
  float m = val;
#pragma unroll
  for (int off = 32; off; off >>= 1) m = fmaxf(m, __shfl_xor(m, off));
  const float e = (lane < 48) ? expf(val - m) : 0.f;
  float ssum = e;
#pragma unroll
  for (int off = 32; off; off >>= 1) ssum += __shfl_xor(ssum, off);
  if (lane < 48) attn[base + r * 48 + lane] = e / ssum;
}

// ---- W_eff^T[img][n][D] = sum_c' A[img][h(D)][c'][D%48] * Wp[48h+c'][n] ----
__global__ __launch_bounds__(256) void make_weff(const float* __restrict__ attn,
                                                 const float* __restrict__ wproj,
                                                 unsigned short* __restrict__ weh,
                                                 unsigned short* __restrict__ wel) {
  const int t = blockIdx.x * 256 + threadIdx.x;   // over NI*192*192
  const int img = t / 36864;
  const int r = t % 36864;
  const int n = r / 192;
  const int D = r % 192;
  const int h = D / 48, dd = D % 48;
  const float* A = &attn[(size_t)(img * 4 + h) * 2304 + dd];
  const float* W = &wproj[(size_t)(h * 48) * 192 + n];
  float acc = 0.f;
#pragma unroll
  for (int c = 0; c < 48; ++c) acc += A[c * 48] * W[c * 192];
  const unsigned short hb = f2bf(acc);
  weh[(size_t)img * 36864 + n * 192 + D] = hb;
  wel[(size_t)img * 36864 + n * 192 + D] = f2bf(acc - bf2f(hb));
}

}  // namespace

extern "C" void kernel_launch(void* const* d_in, const int* in_sizes, int n_in,
                              void* d_out, int out_size, void* d_ws, size_t ws_size,
                              hipStream_t stream) {
  const float* x      = (const float*)d_in[0];
  const float* w_qkv  = (const float*)d_in[1];
  const float* w_dw   = (const float*)d_in[2];
  const float* w_proj = (const float*)d_in[3];
  const float* temp   = (const float*)d_in[4];
  float* out = (float*)d_out;

  // NI images per pass. Layout bytes: NI=2 ≈ 202 MB (ws is 256 MiB), NI=1 ≈ 127 MB.
  auto layout_bytes = [](int NI) -> size_t {
    return (size_t)NI * HW * 576 * 4       // qkv fp32
         + (size_t)NI * HW * 384 * 4       // dwq fp32 (q,k)
         + (size_t)NI * HW * 192 * 2 * 2   // vh, vl
         + (size_t)4 * HW * 192 * 2 * 2    // xh, xl (all 4 images)
         + 2 * 221184                      // wqh, wql
         + (size_t)NI * 38400              // G, ssqq, ssqk
         + (size_t)NI * 147456             // attnb
         + (size_t)NI * 147456;            // weh, wel
  };
  const int NI = (ws_size >= layout_bytes(2)) ? 2 : 1;
  const int npass = 4 / NI;
  const int npix = NI * HW;

  char* p = (char*)d_ws;
  float* qkv = (float*)p;            p += (size_t)npix * 576 * 4;
  float* dwq = (float*)p;            p += (size_t)npix * 384 * 4;
  unsigned short* vh = (unsigned short*)p;  p += (size_t)npix * 192 * 2;
  unsigned short* vl = (unsigned short*)p;  p += (size_t)npix * 192 * 2;
  unsigned short* xh = (unsigned short*)p;  p += (size_t)4 * HW * 192 * 2;
  unsigned short* xl = (unsigned short*)p;  p += (size_t)4 * HW * 192 * 2;
  unsigned short* wqh = (unsigned short*)p; p += 221184;
  unsigned short* wql = (unsigned short*)p; p += 221184;
  float* G    = (float*)p;           p += (size_t)NI * 36864;
  float* ssqq = (float*)p;           p += (size_t)NI * 768;
  float* ssqk = (float*)p;           p += (size_t)NI * 768;
  float* attnb = (float*)p;          p += (size_t)NI * 147456;
  unsigned short* weh = (unsigned short*)p; p += (size_t)NI * 73728;
  unsigned short* wel = (unsigned short*)p;

  cvt_wqkv<<<432, 256, 0, stream>>>(w_qkv, wqh, wql);
  cvt_split<<<4 * HW * 192 / 1024, 256, 0, stream>>>(x, xh, xl);

  for (int pass = 0; pass < npass; ++pass) {
    const size_t arow = (size_t)pass * npix * 192;
    float* outb = out + (size_t)pass * npix * C;
    hipMemsetAsync(G, 0, (size_t)NI * 38400, stream);  // G+ssqq+ssqk contiguous
    gemm_mfma<576, false><<<dim3(npix / 128, 9), 256, 0, stream>>>(
        xh + arow, xl + arow, wqh, wql, qkv);
    dwconv3x3_v2<<<npix * 72 / 256, 256, 0, stream>>>(qkv, w_dw, dwq, vh, vl);
    gram48_v2<<<dim3(256, NI), 256, 0, stream>>>(dwq, G, ssqq, ssqk);
    attn_softmax<<<dim3(48, 4 * NI), 64, 0, stream>>>(G, ssqq, ssqk, temp, attnb);
    make_weff<<<NI * 144, 256, 0, stream>>>(attnb, w_proj, weh, wel);
    gemm_mfma<192, true><<<dim3(npix / 128, 3), 256, 0, stream>>>(
        vh, vl, weh, wel, outb);
  }
}

// Round 6
// 288.681 us; speedup vs baseline: 1.9506x; 1.9506x over previous
//
#include <hip/hip_runtime.h>

namespace {

constexpr int HW = 16384;   // pixels per image
constexpr int C  = 192;
constexpr int C3 = 576;
constexpr int CH = 48;
constexpr int K  = 192;

using bf16x8 = __attribute__((ext_vector_type(8))) short;
using f32x4  = __attribute__((ext_vector_type(4))) float;

__device__ inline unsigned short f2bf(float f) {
  unsigned u = __float_as_uint(f);
  unsigned r = (u + 0x7fff + ((u >> 16) & 1)) >> 16;
  return (unsigned short)r;
}
__device__ inline float bf2f(unsigned short b) {
  return __uint_as_float(((unsigned)b) << 16);
}

// ---- split fp32 -> bf16 hi/lo (4 elems/thread), all images -----------------
__global__ __launch_bounds__(256) void cvt_split(const float* __restrict__ in,
                                                 unsigned short* __restrict__ hi,
                                                 unsigned short* __restrict__ lo) {
  const int t = blockIdx.x * 256 + threadIdx.x;
  const float4 v = ((const float4*)in)[t];
  const float vv[4] = {v.x, v.y, v.z, v.w};
  unsigned short h[4], l[4];
#pragma unroll
  for (int j = 0; j < 4; ++j) {
    h[j] = f2bf(vv[j]);
    l[j] = f2bf(vv[j] - bf2f(h[j]));
  }
  ((ushort4*)hi)[t] = make_ushort4(h[0], h[1], h[2], h[3]);
  ((ushort4*)lo)[t] = make_ushort4(l[0], l[1], l[2], l[3]);
}

// ---- transpose + split qkv weights: [192,576] -> hi/lo [576][192] ----------
__global__ __launch_bounds__(256) void cvt_wqkv(const float* __restrict__ wqkv,
                                                unsigned short* __restrict__ wqh,
                                                unsigned short* __restrict__ wql) {
  const int t = blockIdx.x * 256 + threadIdx.x;  // 0 .. 576*192-1
  const int n = t / 192;
  const int k = t % 192;
  const float v = wqkv[k * C3 + n];
  const unsigned short h = f2bf(v);
  wqh[n * 192 + k] = h;
  wql[n * 192 + k] = f2bf(v - bf2f(h));
}

// ---- MFMA GEMM: Co[M,N] = A[M,192] @ Bt[N,192]^T, 3-pass bf16 split --------
// PERB: B indexed per image (m0>>14).
template <int N, bool PERB>
__global__ __launch_bounds__(256, 3) void gemm_mfma(const unsigned short* __restrict__ Ah,
                                                    const unsigned short* __restrict__ Al,
                                                    const unsigned short* __restrict__ Bh,
                                                    const unsigned short* __restrict__ Bl,
                                                    float* __restrict__ Co) {
  __shared__ __align__(16) unsigned short sAh[2][128 * 32];
  __shared__ __align__(16) unsigned short sAl[2][128 * 32];
  __shared__ __align__(16) unsigned short sBh[2][64 * 32];
  __shared__ __align__(16) unsigned short sBl[2][64 * 32];
  const int t = threadIdx.x;
  const int lane = t & 63;
  const int wid = t >> 6;
  const int m0 = blockIdx.x * 128;
  const int n0 = blockIdx.y * 64;
  const size_t boff = PERB ? (size_t)(m0 >> 14) * (192 * 192) : 0;
  const int wr = wid >> 1, wc = wid & 1;
  const int fr_row = lane & 15;
  const int fr_swz = ((lane >> 4) ^ (lane & 3)) << 3;

  f32x4 acc[4][2] = {};
  bf16x8 rg[6];

  auto stage_load = [&](int k0) {
#pragma unroll
    for (int r = 0; r < 2; ++r) {
      const int idx = t + (r << 8);
      const int row = idx >> 2, sl = idx & 3;
      const size_t go = (size_t)(m0 + row) * K + k0 + (sl << 3);
      rg[r]     = *(const bf16x8*)&Ah[go];
      rg[2 + r] = *(const bf16x8*)&Al[go];
    }
    {
      const int row = t >> 2, sl = t & 3;
      const size_t go = boff + (size_t)(n0 + row) * K + k0 + (sl << 3);
      rg[4] = *(const bf16x8*)&Bh[go];
      rg[5] = *(const bf16x8*)&Bl[go];
    }
  };
  auto stage_write = [&](int buf) {
#pragma unroll
    for (int r = 0; r < 2; ++r) {
      const int idx = t + (r << 8);
      const int row = idx >> 2, sl = idx & 3;
      const int ph = row * 32 + ((sl ^ (row & 3)) << 3);
      *(bf16x8*)&sAh[buf][ph] = rg[r];
      *(bf16x8*)&sAl[buf][ph] = rg[2 + r];
    }
    {
      const int row = t >> 2, sl = t & 3;
      const int ph = row * 32 + ((sl ^ (row & 3)) << 3);
      *(bf16x8*)&sBh[buf][ph] = rg[4];
      *(bf16x8*)&sBl[buf][ph] = rg[5];
    }
  };

  stage_load(0);
  stage_write(0);
  __syncthreads();
#pragma unroll
  for (int ks = 0; ks < 6; ++ks) {
    if (ks < 5) stage_load((ks + 1) * 32);
    {
      const int buf = ks & 1;
      bf16x8 fah[4], fal[4], fbh[2], fbl[2];
#pragma unroll
      for (int i = 0; i < 4; ++i) {
        const int row = wr * 64 + i * 16 + fr_row;
        fah[i] = *(const bf16x8*)&sAh[buf][row * 32 + fr_swz];
        fal[i] = *(const bf16x8*)&sAl[buf][row * 32 + fr_swz];
      }
#pragma unroll
      for (int j = 0; j < 2; ++j) {
        const int row = wc * 32 + j * 16 + fr_row;
        fbh[j] = *(const bf16x8*)&sBh[buf][row * 32 + fr_swz];
        fbl[j] = *(const bf16x8*)&sBl[buf][row * 32 + fr_swz];
      }
#pragma unroll
      for (int i = 0; i < 4; ++i)
#pragma unroll
        for (int j = 0; j < 2; ++j) {
          acc[i][j] = __builtin_amdgcn_mfma_f32_16x16x32_bf16(fah[i], fbh[j], acc[i][j], 0, 0, 0);
          acc[i][j] = __builtin_amdgcn_mfma_f32_16x16x32_bf16(fah[i], fbl[j], acc[i][j], 0, 0, 0);
          acc[i][j] = __builtin_amdgcn_mfma_f32_16x16x32_bf16(fal[i], fbh[j], acc[i][j], 0, 0, 0);
        }
    }
    if (ks < 5) {
      __syncthreads();
      stage_write((ks + 1) & 1);
      __syncthreads();
    }
  }

  const int er = (lane >> 4) << 2;  // C/D: col=lane&15, row=(lane>>4)*4+reg
  const int ec = lane & 15;
#pragma unroll
  for (int i = 0; i < 4; ++i)
#pragma unroll
    for (int j = 0; j < 2; ++j) {
      float* cp = &Co[(size_t)(m0 + wr * 64 + i * 16 + er) * N + n0 + wc * 32 + j * 16 + ec];
#pragma unroll
      for (int r = 0; r < 4; ++r) cp[(size_t)r * N] = acc[i][j][r];
    }
}

// ---- depthwise 3x3 SAME, y-blocked x2; q,k -> fp32 [p][384], v -> bf16 -----
__global__ __launch_bounds__(256) void dwconv3x3_v2(const float* __restrict__ in,
                                                    const float* __restrict__ wdw,
                                                    float* __restrict__ dwq,
                                                    unsigned short* __restrict__ vh,
                                                    unsigned short* __restrict__ vl) {
  const int t = blockIdx.x * 256 + threadIdx.x;
  const int c4 = t % 144;
  const int pix2 = t / 144;          // (img, y-pair, x)
  const int x = pix2 & 127;
  const int yp = (pix2 >> 7) & 63;
  const int img = pix2 >> 13;
  const int y0 = yp * 2;

  // weights: 9 float4 (L1/L2 resident)
  float4 wt[3][3];
#pragma unroll
  for (int i = 0; i < 3; ++i)
#pragma unroll
    for (int j = 0; j < 3; ++j)
      wt[i][j] = *(const float4*)&wdw[(size_t)(i * 3 + j) * C3 + c4 * 4];

  float4 tap[4][3];
  const bool interior = ((unsigned)(x - 1) < 126u) && ((unsigned)(yp - 1) < 62u);
  if (interior) {
    const float* base = &in[((size_t)(img << 14) + (y0 << 7) + x) * C3 + c4 * 4];
#pragma unroll
    for (int i = 0; i < 4; ++i)
#pragma unroll
      for (int j = 0; j < 3; ++j)
        tap[i][j] = *(const float4*)&base[(size_t)((i - 1) * 128 + (j - 1)) * C3];
  } else {
#pragma unroll
    for (int i = 0; i < 4; ++i) {
      const int ry = y0 - 1 + i;
      const int ryc = ry < 0 ? 0 : (ry > 127 ? 127 : ry);
      const bool vy = (unsigned)ry < 128u;
#pragma unroll
      for (int j = 0; j < 3; ++j) {
        const int rx = x - 1 + j;
        const int rxc = rx < 0 ? 0 : (rx > 127 ? 127 : rx);
        float4 v = *(const float4*)&in[((size_t)(img << 14) + (ryc << 7) + rxc) * C3 + c4 * 4];
        if (!(vy && ((unsigned)rx < 128u))) v = make_float4(0.f, 0.f, 0.f, 0.f);
        tap[i][j] = v;
      }
    }
  }

  float4 out0 = make_float4(0.f, 0.f, 0.f, 0.f);
  float4 out1 = make_float4(0.f, 0.f, 0.f, 0.f);
#pragma unroll
  for (int i = 0; i < 3; ++i)
#pragma unroll
    for (int j = 0; j < 3; ++j) {
      const float4 w = wt[i][j];
      const float4 a = tap[i][j];
      const float4 b = tap[i + 1][j];
      out0.x += a.x * w.x; out0.y += a.y * w.y; out0.z += a.z * w.z; out0.w += a.w * w.w;
      out1.x += b.x * w.x; out1.y += b.y * w.y; out1.z += b.z * w.z; out1.w += b.w * w.w;
    }

  const int p0 = (img << 14) + (y0 << 7) + x;
  const int p1 = p0 + 128;
  if (c4 < 96) {
    *(float4*)&dwq[(size_t)p0 * 384 + c4 * 4] = out0;
    *(float4*)&dwq[(size_t)p1 * 384 + c4 * 4] = out1;
  } else {
    const int cc = (c4 - 96) * 4;
    const float v0[4] = {out0.x, out0.y, out0.z, out0.w};
    const float v1[4] = {out1.x, out1.y, out1.z, out1.w};
    ushort4 h0, l0, h1, l1;
    unsigned short *h0p = (unsigned short*)&h0, *l0p = (unsigned short*)&l0;
    unsigned short *h1p = (unsigned short*)&h1, *l1p = (unsigned short*)&l1;
#pragma unroll
    for (int j = 0; j < 4; ++j) {
      unsigned short hb = f2bf(v0[j]);
      h0p[j] = hb; l0p[j] = f2bf(v0[j] - bf2f(hb));
      hb = f2bf(v1[j]);
      h1p[j] = hb; l1p[j] = f2bf(v1[j] - bf2f(hb));
    }
    *(ushort4*)&vh[(size_t)p0 * 192 + cc] = h0;
    *(ushort4*)&vl[(size_t)p0 * 192 + cc] = l0;
    *(ushort4*)&vh[(size_t)p1 * 192 + cc] = h1;
    *(ushort4*)&vl[(size_t)p1 * 192 + cc] = l1;
  }
}

// ------- Gram v1: G[img][h][c][d] += sum_s q[s,c]*k[s,d]; + row sum-sq ------
__global__ __launch_bounds__(256) void gram48(const float* __restrict__ dwq,
                                              float* __restrict__ G,
                                              float* __restrict__ ssqq,
                                              float* __restrict__ ssqk) {
  __shared__ float qs[64][48];
  __shared__ float ks[64][48];
  const int tid = threadIdx.x;
  const int h = blockIdx.y;
  const int img = blockIdx.z;
  const int s0 = (img << 14) + blockIdx.x * 256;
  const int qoff = h * CH;
  const int koff = 192 + h * CH;
  const int c3 = (tid >> 4) * 3;
  const int d3 = (tid & 15) * 3;
  float acc[3][3] = {};
  float sq = 0.f, sk = 0.f;
  for (int sub = 0; sub < 4; ++sub) {
    const int sbase = s0 + sub * 64;
#pragma unroll
    for (int r = 0; r < 3; ++r) {
      const int idx = tid + r * 256;
      const int row = idx / 12;
      const int cc4 = idx % 12;
      const float* src = &dwq[(size_t)(sbase + row) * 384];
      *(float4*)&qs[row][cc4 * 4] = *(const float4*)&src[qoff + cc4 * 4];
      *(float4*)&ks[row][cc4 * 4] = *(const float4*)&src[koff + cc4 * 4];
    }
    __syncthreads();
#pragma unroll 4
    for (int s = 0; s < 64; ++s) {
      const float qv[3] = {qs[s][c3], qs[s][c3 + 1], qs[s][c3 + 2]};
      const float kv[3] = {ks[s][d3], ks[s][d3 + 1], ks[s][d3 + 2]};
#pragma unroll
      for (int i = 0; i < 3; ++i)
#pragma unroll
        for (int j = 0; j < 3; ++j) acc[i][j] += qv[i] * kv[j];
    }
    if (tid < 48) {
#pragma unroll 4
      for (int s = 0; s < 64; ++s) { const float v = qs[s][tid]; sq += v * v; }
    } else if (tid >= 64 && tid < 112) {
      const int cc = tid - 64;
#pragma unroll 4
      for (int s = 0; s < 64; ++s) { const float v = ks[s][cc]; sk += v * v; }
    }
    __syncthreads();
  }
  float* Gm = &G[(size_t)(img * 4 + h) * 2304];
#pragma unroll
  for (int i = 0; i < 3; ++i)
#pragma unroll
    for (int j = 0; j < 3; ++j) atomicAdd(&Gm[(c3 + i) * 48 + d3 + j], acc[i][j]);
  if (tid < 48) atomicAdd(&ssqq[img * 192 + h * CH + tid], sq);
  else if (tid >= 64 && tid < 112) atomicAdd(&ssqk[img * 192 + h * CH + tid - 64], sk);
}

// ---- softmax over d of G*temp/(|q||k|), one wave per (img,h,row) -----------
__global__ __launch_bounds__(64) void attn_softmax(const float* __restrict__ G,
                                                   const float* __restrict__ ssqq,
                                                   const float* __restrict__ ssqk,
                                                   const float* __restrict__ temp,
                                                   float* __restrict__ attn) {
  const int r = blockIdx.x;          // 0..47
  const int h = blockIdx.y & 3;
  const int img = blockIdx.y >> 2;
  const int lane = threadIdx.x;
  const size_t base = (size_t)(img * 4 + h) * 2304;
  const float t = temp[h];
  const float qn = ssqq[img * 192 + h * CH + r];
  float val = -1e30f;
  if (lane < 48) {
    const float kn = ssqk[img * 192 + h * CH + lane];
    val = G[base + r * 48 + lane] * t * rsqrtf(qn * kn);
  }
  float m = val;
#pragma unroll
  for (int off = 32; off; off >>= 1) m = fmaxf(m, __shfl_xor(m, off));
  const float e = (lane < 48) ? expf(val - m) : 0.f;
  float ssum = e;
#pragma unroll
  for (int off = 32; off; off >>= 1) ssum += __shfl_xor(ssum, off);
  if (lane < 48) attn[base + r * 48 + lane] = e / ssum;
}

// ---- W_eff^T[img][n][D] = sum_c' A[img][h(D)][c'][D%48] * Wp[48h+c'][n] ----
__global__ __launch_bounds__(256) void make_weff(const float* __restrict__ attn,
                                                 const float* __restrict__ wproj,
                                                 unsigned short* __restrict__ weh,
                                                 unsigned short* __restrict__ wel) {
  const int t = blockIdx.x * 256 + threadIdx.x;   // over NI*192*192
  const int img = t / 36864;
  const int r = t % 36864;
  const int n = r / 192;
  const int D = r % 192;
  const int h = D / 48, dd = D % 48;
  const float* A = &attn[(size_t)(img * 4 + h) * 2304 + dd];
  const float* W = &wproj[(size_t)(h * 48) * 192 + n];
  float acc = 0.f;
#pragma unroll
  for (int c = 0; c < 48; ++c) acc += A[c * 48] * W[c * 192];
  const unsigned short hb = f2bf(acc);
  weh[(size_t)img * 36864 + n * 192 + D] = hb;
  wel[(size_t)img * 36864 + n * 192 + D] = f2bf(acc - bf2f(hb));
}

}  // namespace

extern "C" void kernel_launch(void* const* d_in, const int* in_sizes, int n_in,
                              void* d_out, int out_size, void* d_ws, size_t ws_size,
                              hipStream_t stream) {
  const float* x      = (const float*)d_in[0];
  const float* w_qkv  = (const float*)d_in[1];
  const float* w_dw   = (const float*)d_in[2];
  const float* w_proj = (const float*)d_in[3];
  const float* temp   = (const float*)d_in[4];
  float* out = (float*)d_out;

  // NI images per pass. Layout bytes: NI=2 ≈ 202 MB (ws is 256 MiB), NI=1 ≈ 127 MB.
  auto layout_bytes = [](int NI) -> size_t {
    return (size_t)NI * HW * 576 * 4       // qkv fp32
         + (size_t)NI * HW * 384 * 4       // dwq fp32 (q,k)
         + (size_t)NI * HW * 192 * 2 * 2   // vh, vl
         + (size_t)4 * HW * 192 * 2 * 2    // xh, xl (all 4 images)
         + 2 * 221184                      // wqh, wql
         + (size_t)NI * 38400              // G, ssqq, ssqk
         + (size_t)NI * 147456             // attnb
         + (size_t)NI * 147456;            // weh, wel
  };
  const int NI = (ws_size >= layout_bytes(2)) ? 2 : 1;
  const int npass = 4 / NI;
  const int npix = NI * HW;

  char* p = (char*)d_ws;
  float* qkv = (float*)p;            p += (size_t)npix * 576 * 4;
  float* dwq = (float*)p;            p += (size_t)npix * 384 * 4;
  unsigned short* vh = (unsigned short*)p;  p += (size_t)npix * 192 * 2;
  unsigned short* vl = (unsigned short*)p;  p += (size_t)npix * 192 * 2;
  unsigned short* xh = (unsigned short*)p;  p += (size_t)4 * HW * 192 * 2;
  unsigned short* xl = (unsigned short*)p;  p += (size_t)4 * HW * 192 * 2;
  unsigned short* wqh = (unsigned short*)p; p += 221184;
  unsigned short* wql = (unsigned short*)p; p += 221184;
  float* G    = (float*)p;           p += (size_t)NI * 36864;
  float* ssqq = (float*)p;           p += (size_t)NI * 768;
  float* ssqk = (float*)p;           p += (size_t)NI * 768;
  float* attnb = (float*)p;          p += (size_t)NI * 147456;
  unsigned short* weh = (unsigned short*)p; p += (size_t)NI * 73728;
  unsigned short* wel = (unsigned short*)p;

  cvt_wqkv<<<432, 256, 0, stream>>>(w_qkv, wqh, wql);
  cvt_split<<<4 * HW * 192 / 1024, 256, 0, stream>>>(x, xh, xl);

  for (int pass = 0; pass < npass; ++pass) {
    const size_t arow = (size_t)pass * npix * 192;
    float* outb = out + (size_t)pass * npix * C;
    hipMemsetAsync(G, 0, (size_t)NI * 38400, stream);  // G+ssqq+ssqk contiguous
    gemm_mfma<576, false><<<dim3(npix / 128, 9), 256, 0, stream>>>(
        xh + arow, xl + arow, wqh, wql, qkv);
    dwconv3x3_v2<<<npix * 72 / 256, 256, 0, stream>>>(qkv, w_dw, dwq, vh, vl);
    gram48<<<dim3(64, 4, NI), 256, 0, stream>>>(dwq, G, ssqq, ssqk);
    attn_softmax<<<dim3(48, 4 * NI), 64, 0, stream>>>(G, ssqq, ssqk, temp, attnb);
    make_weff<<<NI * 144, 256, 0, stream>>>(attnb, w_proj, weh, wel);
    gemm_mfma<192, true><<<dim3(npix / 128, 3), 256, 0, stream>>>(
        vh, vl, weh, wel, outb);
  }
}

// Round 7
// 249.786 us; speedup vs baseline: 2.2543x; 1.1557x over previous
//
#include <hip/hip_runtime.h>

namespace {

constexpr int HW = 16384;   // pixels per image
constexpr int C  = 192;
constexpr int C3 = 576;
constexpr int CH = 48;
constexpr int K  = 192;

using bf16x8 = __attribute__((ext_vector_type(8))) short;
using f32x4  = __attribute__((ext_vector_type(4))) float;

__device__ inline unsigned short f2bf(float f) {
  unsigned u = __float_as_uint(f);
  unsigned r = (u + 0x7fff + ((u >> 16) & 1)) >> 16;
  return (unsigned short)r;
}
__device__ inline float bf2f(unsigned short b) {
  return __uint_as_float(((unsigned)b) << 16);
}

// ---- split fp32 -> bf16 hi/lo (4 elems/thread), all images -----------------
__global__ __launch_bounds__(256) void cvt_split(const float* __restrict__ in,
                                                 unsigned short* __restrict__ hi,
                                                 unsigned short* __restrict__ lo) {
  const int t = blockIdx.x * 256 + threadIdx.x;
  const float4 v = ((const float4*)in)[t];
  const float vv[4] = {v.x, v.y, v.z, v.w};
  unsigned short h[4], l[4];
#pragma unroll
  for (int j = 0; j < 4; ++j) {
    h[j] = f2bf(vv[j]);
    l[j] = f2bf(vv[j] - bf2f(h[j]));
  }
  ((ushort4*)hi)[t] = make_ushort4(h[0], h[1], h[2], h[3]);
  ((ushort4*)lo)[t] = make_ushort4(l[0], l[1], l[2], l[3]);
}

// ---- transpose + split qkv weights: [192,576] -> hi/lo [576][192] ----------
__global__ __launch_bounds__(256) void cvt_wqkv(const float* __restrict__ wqkv,
                                                unsigned short* __restrict__ wqh,
                                                unsigned short* __restrict__ wql) {
  const int t = blockIdx.x * 256 + threadIdx.x;  // 0 .. 576*192-1
  const int n = t / 192;
  const int k = t % 192;
  const float v = wqkv[k * C3 + n];
  const unsigned short h = f2bf(v);
  wqh[n * 192 + k] = h;
  wql[n * 192 + k] = f2bf(v - bf2f(h));
}

// ---- MFMA GEMM: Co[M,N] = A[M,192] @ Bt[N,192]^T, 3-pass bf16 split --------
// PERB: B indexed per image (m0>>14).
template <int N, bool PERB>
__global__ __launch_bounds__(256, 3) void gemm_mfma(const unsigned short* __restrict__ Ah,
                                                    const unsigned short* __restrict__ Al,
                                                    const unsigned short* __restrict__ Bh,
                                                    const unsigned short* __restrict__ Bl,
                                                    float* __restrict__ Co) {
  __shared__ __align__(16) unsigned short sAh[2][128 * 32];
  __shared__ __align__(16) unsigned short sAl[2][128 * 32];
  __shared__ __align__(16) unsigned short sBh[2][64 * 32];
  __shared__ __align__(16) unsigned short sBl[2][64 * 32];
  const int t = threadIdx.x;
  const int lane = t & 63;
  const int wid = t >> 6;
  const int m0 = blockIdx.x * 128;
  const int n0 = blockIdx.y * 64;
  const size_t boff = PERB ? (size_t)(m0 >> 14) * (192 * 192) : 0;
  const int wr = wid >> 1, wc = wid & 1;
  const int fr_row = lane & 15;
  const int fr_swz = ((lane >> 4) ^ (lane & 3)) << 3;

  f32x4 acc[4][2] = {};
  bf16x8 rg[6];

  auto stage_load = [&](int k0) {
#pragma unroll
    for (int r = 0; r < 2; ++r) {
      const int idx = t + (r << 8);
      const int row = idx >> 2, sl = idx & 3;
      const size_t go = (size_t)(m0 + row) * K + k0 + (sl << 3);
      rg[r]     = *(const bf16x8*)&Ah[go];
      rg[2 + r] = *(const bf16x8*)&Al[go];
    }
    {
      const int row = t >> 2, sl = t & 3;
      const size_t go = boff + (size_t)(n0 + row) * K + k0 + (sl << 3);
      rg[4] = *(const bf16x8*)&Bh[go];
      rg[5] = *(const bf16x8*)&Bl[go];
    }
  };
  auto stage_write = [&](int buf) {
#pragma unroll
    for (int r = 0; r < 2; ++r) {
      const int idx = t + (r << 8);
      const int row = idx >> 2, sl = idx & 3;
      const int ph = row * 32 + ((sl ^ (row & 3)) << 3);
      *(bf16x8*)&sAh[buf][ph] = rg[r];
      *(bf16x8*)&sAl[buf][ph] = rg[2 + r];
    }
    {
      const int row = t >> 2, sl = t & 3;
      const int ph = row * 32 + ((sl ^ (row & 3)) << 3);
      *(bf16x8*)&sBh[buf][ph] = rg[4];
      *(bf16x8*)&sBl[buf][ph] = rg[5];
    }
  };

  stage_load(0);
  stage_write(0);
  __syncthreads();
#pragma unroll
  for (int ks = 0; ks < 6; ++ks) {
    if (ks < 5) stage_load((ks + 1) * 32);
    {
      const int buf = ks & 1;
      bf16x8 fah[4], fal[4], fbh[2], fbl[2];
#pragma unroll
      for (int i = 0; i < 4; ++i) {
        const int row = wr * 64 + i * 16 + fr_row;
        fah[i] = *(const bf16x8*)&sAh[buf][row * 32 + fr_swz];
        fal[i] = *(const bf16x8*)&sAl[buf][row * 32 + fr_swz];
      }
#pragma unroll
      for (int j = 0; j < 2; ++j) {
        const int row = wc * 32 + j * 16 + fr_row;
        fbh[j] = *(const bf16x8*)&sBh[buf][row * 32 + fr_swz];
        fbl[j] = *(const bf16x8*)&sBl[buf][row * 32 + fr_swz];
      }
#pragma unroll
      for (int i = 0; i < 4; ++i)
#pragma unroll
        for (int j = 0; j < 2; ++j) {
          acc[i][j] = __builtin_amdgcn_mfma_f32_16x16x32_bf16(fah[i], fbh[j], acc[i][j], 0, 0, 0);
          acc[i][j] = __builtin_amdgcn_mfma_f32_16x16x32_bf16(fah[i], fbl[j], acc[i][j], 0, 0, 0);
          acc[i][j] = __builtin_amdgcn_mfma_f32_16x16x32_bf16(fal[i], fbh[j], acc[i][j], 0, 0, 0);
        }
    }
    if (ks < 5) {
      __syncthreads();
      stage_write((ks + 1) & 1);
      __syncthreads();
    }
  }

  const int er = (lane >> 4) << 2;  // C/D: col=lane&15, row=(lane>>4)*4+reg
  const int ec = lane & 15;
#pragma unroll
  for (int i = 0; i < 4; ++i)
#pragma unroll
    for (int j = 0; j < 2; ++j) {
      float* cp = &Co[(size_t)(m0 + wr * 64 + i * 16 + er) * N + n0 + wc * 32 + j * 16 + ec];
#pragma unroll
      for (int r = 0; r < 4; ++r) cp[(size_t)r * N] = acc[i][j][r];
    }
}

// ---- depthwise 3x3 SAME, y-blocked x2 --------------------------------------
// q,k -> packed uint (hi | lo<<16) qkp[p][384]; v -> bf16 hi/lo [p][192]
__global__ __launch_bounds__(256) void dwconv3x3_v2(const float* __restrict__ in,
                                                    const float* __restrict__ wdw,
                                                    unsigned int* __restrict__ qkp,
                                                    unsigned short* __restrict__ vh,
                                                    unsigned short* __restrict__ vl) {
  const int t = blockIdx.x * 256 + threadIdx.x;
  const int c4 = t % 144;
  const int pix2 = t / 144;          // (img, y-pair, x)
  const int x = pix2 & 127;
  const int yp = (pix2 >> 7) & 63;
  const int img = pix2 >> 13;
  const int y0 = yp * 2;

  float4 wt[3][3];
#pragma unroll
  for (int i = 0; i < 3; ++i)
#pragma unroll
    for (int j = 0; j < 3; ++j)
      wt[i][j] = *(const float4*)&wdw[(size_t)(i * 3 + j) * C3 + c4 * 4];

  float4 tap[4][3];
  const bool interior = ((unsigned)(x - 1) < 126u) && ((unsigned)(yp - 1) < 62u);
  if (interior) {
    const float* base = &in[((size_t)(img << 14) + (y0 << 7) + x) * C3 + c4 * 4];
#pragma unroll
    for (int i = 0; i < 4; ++i)
#pragma unroll
      for (int j = 0; j < 3; ++j)
        tap[i][j] = *(const float4*)&base[(size_t)((i - 1) * 128 + (j - 1)) * C3];
  } else {
#pragma unroll
    for (int i = 0; i < 4; ++i) {
      const int ry = y0 - 1 + i;
      const int ryc = ry < 0 ? 0 : (ry > 127 ? 127 : ry);
      const bool vy = (unsigned)ry < 128u;
#pragma unroll
      for (int j = 0; j < 3; ++j) {
        const int rx = x - 1 + j;
        const int rxc = rx < 0 ? 0 : (rx > 127 ? 127 : rx);
        float4 v = *(const float4*)&in[((size_t)(img << 14) + (ryc << 7) + rxc) * C3 + c4 * 4];
        if (!(vy && ((unsigned)rx < 128u))) v = make_float4(0.f, 0.f, 0.f, 0.f);
        tap[i][j] = v;
      }
    }
  }

  float4 out0 = make_float4(0.f, 0.f, 0.f, 0.f);
  float4 out1 = make_float4(0.f, 0.f, 0.f, 0.f);
#pragma unroll
  for (int i = 0; i < 3; ++i)
#pragma unroll
    for (int j = 0; j < 3; ++j) {
      const float4 w = wt[i][j];
      const float4 a = tap[i][j];
      const float4 b = tap[i + 1][j];
      out0.x += a.x * w.x; out0.y += a.y * w.y; out0.z += a.z * w.z; out0.w += a.w * w.w;
      out1.x += b.x * w.x; out1.y += b.y * w.y; out1.z += b.z * w.z; out1.w += b.w * w.w;
    }

  const int p0 = (img << 14) + (y0 << 7) + x;
  const int p1 = p0 + 128;
  const float v0[4] = {out0.x, out0.y, out0.z, out0.w};
  const float v1[4] = {out1.x, out1.y, out1.z, out1.w};
  if (c4 < 96) {
    // q (c4<48) -> cols 4c4..; k (48<=c4<96) -> cols 192+(c4-48)*4 == 4c4
    uint4 a, b;
    unsigned* ap = (unsigned*)&a;
    unsigned* bp = (unsigned*)&b;
#pragma unroll
    for (int j = 0; j < 4; ++j) {
      unsigned short h0 = f2bf(v0[j]);
      unsigned short l0 = f2bf(v0[j] - bf2f(h0));
      ap[j] = (unsigned)h0 | ((unsigned)l0 << 16);
      unsigned short h1 = f2bf(v1[j]);
      unsigned short l1 = f2bf(v1[j] - bf2f(h1));
      bp[j] = (unsigned)h1 | ((unsigned)l1 << 16);
    }
    *(uint4*)&qkp[(size_t)p0 * 384 + c4 * 4] = a;
    *(uint4*)&qkp[(size_t)p1 * 384 + c4 * 4] = b;
  } else {
    const int cc = (c4 - 96) * 4;
    ushort4 h0, l0, h1, l1;
    unsigned short *h0p = (unsigned short*)&h0, *l0p = (unsigned short*)&l0;
    unsigned short *h1p = (unsigned short*)&h1, *l1p = (unsigned short*)&l1;
#pragma unroll
    for (int j = 0; j < 4; ++j) {
      unsigned short hb = f2bf(v0[j]);
      h0p[j] = hb; l0p[j] = f2bf(v0[j] - bf2f(hb));
      hb = f2bf(v1[j]);
      h1p[j] = hb; l1p[j] = f2bf(v1[j] - bf2f(hb));
    }
    *(ushort4*)&vh[(size_t)p0 * 192 + cc] = h0;
    *(ushort4*)&vl[(size_t)p0 * 192 + cc] = l0;
    *(ushort4*)&vh[(size_t)p1 * 192 + cc] = h1;
    *(ushort4*)&vl[(size_t)p1 * 192 + cc] = l1;
  }
}

// ------- Gram v3 (MFMA): G = Q^T K per (img,h), 3-pass bf16; + ssq ----------
// qkp packed [npix][384]: q cols 0..191, k cols 192..383, value = hi | lo<<16.
// Block: 256 px chunk, 2 rounds of 128 px staged [128][48] (W=50 uint pad).
// Both MFMA operands are column reads of [s][ch] (K-dim = pixels).
__global__ __launch_bounds__(256) void gram48_mfma(const unsigned int* __restrict__ qkp,
                                                   float* __restrict__ G,
                                                   float* __restrict__ ssqq,
                                                   float* __restrict__ ssqk) {
  constexpr int W = 50;
  __shared__ unsigned int smem[2 * 128 * W];   // sq | sk; reused as f32 reduce buf
  unsigned int* sq = smem;
  unsigned int* sk = smem + 128 * W;
  const int tid = threadIdx.x;
  const int lane = tid & 63;
  const int wv = tid >> 6;
  const int pair = blockIdx.y;          // img*4 + h
  const int img = pair >> 2, h = pair & 3;
  const int qcol = h * 48;
  const int kcol = 192 + h * 48;

  f32x4 acc[3][3] = {};
  float ssq_acc = 0.f;
  const int sch = tid % 96;             // ssq channel (threads < 192)
  const int shalf = tid / 96;

  for (int rnd = 0; rnd < 2; ++rnd) {
    const int sbase = (img << 14) + blockIdx.x * 256 + rnd * 128;
#pragma unroll
    for (int r = 0; r < 6; ++r) {
      const int idx = tid + (r << 8);    // 0..1535 = 128 rows x 12 uint4
      const int row = idx / 12, cc = (idx % 12) * 4;
      const uint4 vq = *(const uint4*)&qkp[(size_t)(sbase + row) * 384 + qcol + cc];
      const uint4 vk = *(const uint4*)&qkp[(size_t)(sbase + row) * 384 + kcol + cc];
      unsigned int* dq = &sq[row * W + cc];
      unsigned int* dk = &sk[row * W + cc];
      *(uint2*)dq = make_uint2(vq.x, vq.y);
      *(uint2*)(dq + 2) = make_uint2(vq.z, vq.w);
      *(uint2*)dk = make_uint2(vk.x, vk.y);
      *(uint2*)(dk + 2) = make_uint2(vk.z, vk.w);
    }
    __syncthreads();
    {
      // wave wv owns s-local [32wv, 32wv+32); frag k-slice = 8*(lane>>4)+j
      const int s0 = wv * 32 + ((lane >> 4) << 3);
      const int cm = lane & 15;
      bf16x8 qh[3], ql[3], kh[3], kl[3];
#pragma unroll
      for (int t3 = 0; t3 < 3; ++t3) {
#pragma unroll
        for (int j = 0; j < 8; ++j) {
          const unsigned int uq = sq[(s0 + j) * W + t3 * 16 + cm];
          const unsigned int uk = sk[(s0 + j) * W + t3 * 16 + cm];
          qh[t3][j] = (short)(uq & 0xffffu);
          ql[t3][j] = (short)(uq >> 16);
          kh[t3][j] = (short)(uk & 0xffffu);
          kl[t3][j] = (short)(uk >> 16);
        }
      }
#pragma unroll
      for (int mt = 0; mt < 3; ++mt)
#pragma unroll
        for (int nt = 0; nt < 3; ++nt) {
          acc[mt][nt] = __builtin_amdgcn_mfma_f32_16x16x32_bf16(qh[mt], kh[nt], acc[mt][nt], 0, 0, 0);
          acc[mt][nt] = __builtin_amdgcn_mfma_f32_16x16x32_bf16(qh[mt], kl[nt], acc[mt][nt], 0, 0, 0);
          acc[mt][nt] = __builtin_amdgcn_mfma_f32_16x16x32_bf16(ql[mt], kh[nt], acc[mt][nt], 0, 0, 0);
        }
    }
    if (tid < 192) {
      const unsigned int* srcb = (sch < 48) ? &sq[sch] : &sk[sch - 48];
      const int sstart = shalf * 64;
#pragma unroll 4
      for (int s = 0; s < 64; ++s) {
        const unsigned int u = srcb[(size_t)(sstart + s) * W];
        const float v = bf2f((unsigned short)(u & 0xffffu)) + bf2f((unsigned short)(u >> 16));
        ssq_acc += v * v;
      }
    }
    __syncthreads();
  }

  // block reduce 4 wave-partials (reuse smem as floats), then atomics
  float* red = (float*)smem;
  const int col = lane & 15;
  const int rbase = (lane >> 4) * 4;
#pragma unroll
  for (int mt = 0; mt < 3; ++mt)
#pragma unroll
    for (int nt = 0; nt < 3; ++nt)
#pragma unroll
      for (int rg = 0; rg < 4; ++rg)
        red[wv * 2304 + (mt * 16 + rbase + rg) * 48 + nt * 16 + col] = acc[mt][nt][rg];
  __syncthreads();
  float* Gm = &G[(size_t)pair * 2304];
#pragma unroll
  for (int c = 0; c < 9; ++c) {
    const int cell = tid + (c << 8);
    const float s4 = red[cell] + red[2304 + cell] + red[4608 + cell] + red[6912 + cell];
    atomicAdd(&Gm[cell], s4);
  }
  if (tid < 192) {
    if (sch < 48) atomicAdd(&ssqq[img * 192 + h * 48 + sch], ssq_acc);
    else          atomicAdd(&ssqk[img * 192 + h * 48 + sch - 48], ssq_acc);
  }
}

// ---- softmax over d of G*temp/(|q||k|), one wave per (img,h,row) -----------
__global__ __launch_bounds__(64) void attn_softmax(const float* __restrict__ G,
                                                   const float* __restrict__ ssqq,
                                                   const float* __restrict__ ssqk,
                                                   const float* __restrict__ temp,
                                                   float* __restrict__ attn) {
  const int r = blockIdx.x;          // 0..47
  const int h = blockIdx.y & 3;
  const int img = blockIdx.y >> 2;
  const int lane = threadIdx.x;
  const size_t base = (size_t)(img * 4 + h) * 2304;
  const float t = temp[h];
  const float qn = ssqq[img * 192 + h * CH + r];
  float val = -1e30f;
  if (lane < 48) {
    const float kn = ssqk[img * 192 + h * CH + lane];
    val = G[base + r * 48 + lane] * t * rsqrtf(qn * kn);
  }
  float m = val;
#pragma unroll
  for (int off = 32; off; off >>= 1) m = fmaxf(m, __shfl_xor(m, off));
  const float e = (lane < 48) ? expf(val - m) : 0.f;
  float ssum = e;
#pragma unroll
  for (int off = 32; off; off >>= 1) ssum += __shfl_xor(ssum, off);
  if (lane < 48) attn[base + r * 48 + lane] = e / ssum;
}

// ---- W_eff^T[img][n][D] = sum_c' A[img][h(D)][c'][D%48] * Wp[48h+c'][n] ----
__global__ __launch_bounds__(256) void make_weff(const float* __restrict__ attn,
                                                 const float* __restrict__ wproj,
                                                 unsigned short* __restrict__ weh,
                                                 unsigned short* __restrict__ wel) {
  const int t = blockIdx.x * 256 + threadIdx.x;   // over NI*192*192
  const int img = t / 36864;
  const int r = t % 36864;
  const int n = r / 192;
  const int D = r % 192;
  const int h = D / 48, dd = D % 48;
  const float* A = &attn[(size_t)(img * 4 + h) * 2304 + dd];
  const float* Wp = &wproj[(size_t)(h * 48) * 192 + n];
  float acc = 0.f;
#pragma unroll
  for (int c = 0; c < 48; ++c) acc += A[c * 48] * Wp[c * 192];
  const unsigned short hb = f2bf(acc);
  weh[(size_t)img * 36864 + n * 192 + D] = hb;
  wel[(size_t)img * 36864 + n * 192 + D] = f2bf(acc - bf2f(hb));
}

}  // namespace

extern "C" void kernel_launch(void* const* d_in, const int* in_sizes, int n_in,
                              void* d_out, int out_size, void* d_ws, size_t ws_size,
                              hipStream_t stream) {
  const float* x      = (const float*)d_in[0];
  const float* w_qkv  = (const float*)d_in[1];
  const float* w_dw   = (const float*)d_in[2];
  const float* w_proj = (const float*)d_in[3];
  const float* temp   = (const float*)d_in[4];
  float* out = (float*)d_out;

  // NI images per pass. Layout bytes: NI=2 ≈ 202 MB (ws is 256 MiB), NI=1 ≈ 127 MB.
  auto layout_bytes = [](int NI) -> size_t {
    return (size_t)NI * HW * 576 * 4       // qkv fp32
         + (size_t)NI * HW * 384 * 4       // qkp packed uint (q,k hi|lo)
         + (size_t)NI * HW * 192 * 2 * 2   // vh, vl
         + (size_t)4 * HW * 192 * 2 * 2    // xh, xl (all 4 images)
         + 2 * 221184                      // wqh, wql
         + (size_t)NI * 38400              // G, ssqq, ssqk
         + (size_t)NI * 147456             // attnb
         + (size_t)NI * 147456;            // weh, wel
  };
  const int NI = (ws_size >= layout_bytes(2)) ? 2 : 1;
  const int npass = 4 / NI;
  const int npix = NI * HW;

  char* p = (char*)d_ws;
  float* qkv = (float*)p;            p += (size_t)npix * 576 * 4;
  unsigned int* qkp = (unsigned int*)p;     p += (size_t)npix * 384 * 4;
  unsigned short* vh = (unsigned short*)p;  p += (size_t)npix * 192 * 2;
  unsigned short* vl = (unsigned short*)p;  p += (size_t)npix * 192 * 2;
  unsigned short* xh = (unsigned short*)p;  p += (size_t)4 * HW * 192 * 2;
  unsigned short* xl = (unsigned short*)p;  p += (size_t)4 * HW * 192 * 2;
  unsigned short* wqh = (unsigned short*)p; p += 221184;
  unsigned short* wql = (unsigned short*)p; p += 221184;
  float* G    = (float*)p;           p += (size_t)NI * 36864;
  float* ssqq = (float*)p;           p += (size_t)NI * 768;
  float* ssqk = (float*)p;           p += (size_t)NI * 768;
  float* attnb = (float*)p;          p += (size_t)NI * 147456;
  unsigned short* weh = (unsigned short*)p; p += (size_t)NI * 73728;
  unsigned short* wel = (unsigned short*)p;

  cvt_wqkv<<<432, 256, 0, stream>>>(w_qkv, wqh, wql);
  cvt_split<<<4 * HW * 192 / 1024, 256, 0, stream>>>(x, xh, xl);

  for (int pass = 0; pass < npass; ++pass) {
    const size_t arow = (size_t)pass * npix * 192;
    float* outb = out + (size_t)pass * npix * C;
    hipMemsetAsync(G, 0, (size_t)NI * 38400, stream);  // G+ssqq+ssqk contiguous
    gemm_mfma<576, false><<<dim3(npix / 128, 9), 256, 0, stream>>>(
        xh + arow, xl + arow, wqh, wql, qkv);
    dwconv3x3_v2<<<npix * 72 / 256, 256, 0, stream>>>(qkv, w_dw, qkp, vh, vl);
    gram48_mfma<<<dim3(64, 4 * NI), 256, 0, stream>>>(qkp, G, ssqq, ssqk);
    attn_softmax<<<dim3(48, 4 * NI), 64, 0, stream>>>(G, ssqq, ssqk, temp, attnb);
    make_weff<<<NI * 144, 256, 0, stream>>>(attnb, w_proj, weh, wel);
    gemm_mfma<192, true><<<dim3(npix / 128, 3), 256, 0, stream>>>(
        vh, vl, weh, wel, outb);
  }
}